// Round 1
// baseline (227.768 us; speedup 1.0000x reference)
//
#include <hip/hip_runtime.h>
#include <cstdint>
#include <cstddef>

typedef _Float16 h16;
typedef __attribute__((ext_vector_type(8))) _Float16 half8;
typedef __attribute__((ext_vector_type(2))) _Float16 half2v;
typedef __attribute__((ext_vector_type(4))) float f32x4;
typedef __attribute__((ext_vector_type(2))) float f32x2;

#define NB 16384
#define NTAB 26
#define NR 100000

__device__ __forceinline__ void gload16(const void* g, void* l) {
  __builtin_amdgcn_global_load_lds(
      (const __attribute__((address_space(1))) unsigned int*)g,
      (__attribute__((address_space(3))) unsigned int*)l, 16, 0, 0);
}

// ---- bottom layer 0: Y[B,512] = relu(x[B,13] @ W0[512,13]^T + b0), fp16 out
__global__ __launch_bounds__(256) void bot0_k(
    const float* __restrict__ x, const float* __restrict__ W,
    const float* __restrict__ bias, h16* __restrict__ Y) {
  int gid = blockIdx.x * 256 + threadIdx.x;
  int row = gid >> 9;
  int n = gid & 511;
  const float* xr = x + row * 13;
  const float* wr = W + n * 13;
  float acc = bias[n];
#pragma unroll
  for (int k = 0; k < 13; ++k) acc += xr[k] * wr[k];
  Y[gid] = (h16)fmaxf(acc, 0.f);
}

// ---- generic f32 -> fp16 with K padding: src[N,K] -> dst[N,Kp]
__global__ void cvt_k(const float* __restrict__ src, h16* __restrict__ dst,
                      int N, int K, int Kp) {
  int i = blockIdx.x * 256 + threadIdx.x;
  if (i >= N * Kp) return;
  int n = i / Kp, k = i - n * Kp;
  dst[i] = (k < K) ? (h16)src[(size_t)n * K + k] : (h16)0.f;
}

// ---- fp16 MFMA GEMM: C[M,N] = relu(A[M,K] @ W[N,K]^T + bias)
// 128x128 tile, BK=64, 4 waves (2x2 of 64x64), global_load_lds staging with
// XOR-swizzled global source so ds_read_b128 fragment reads are conflict-free.
__global__ __launch_bounds__(256, 2) void gemm_h(
    const h16* __restrict__ A, const h16* __restrict__ W,
    const float* __restrict__ bias, h16* __restrict__ C, int N, int K) {
  __shared__ __align__(16) h16 As[128 * 64];
  __shared__ __align__(16) h16 Bs[128 * 64];
  const int tid = threadIdx.x;
  const int lane = tid & 63;
  const int wave = tid >> 6;
  const int wm = wave >> 1, wn = wave & 1;
  const size_t row0 = (size_t)blockIdx.x * 128;
  const size_t col0 = (size_t)blockIdx.y * 128;
  const int lr = lane >> 3;                   // staging: local row within 8-row chunk
  const int swzc = (((lane & 7) ^ lr) << 3);  // swizzled source k-block (elems)
  const int l15 = lane & 15;
  const int kq = lane >> 4;  // 0..3
  const int l7 = lane & 7;

  f32x4 acc[4][4] = {};

  for (int k0 = 0; k0 < K; k0 += 64) {
    __syncthreads();
    const h16* ga = A + (row0 + wave * 32 + lr) * (size_t)K + k0 + swzc;
    const h16* gb = W + (col0 + wave * 32 + lr) * (size_t)K + k0 + swzc;
    h16* la = As + wave * 32 * 64;
    h16* lb = Bs + wave * 32 * 64;
#pragma unroll
    for (int i = 0; i < 4; ++i) {
      gload16(ga + (size_t)i * 8 * K, la + i * 8 * 64);
      gload16(gb + (size_t)i * 8 * K, lb + i * 8 * 64);
    }
    asm volatile("s_waitcnt vmcnt(0)" ::: "memory");
    __syncthreads();
#pragma unroll
    for (int kk = 0; kk < 2; ++kk) {
      half8 a[4], b[4];
      const int kb = kk * 4 + kq;
#pragma unroll
      for (int mi = 0; mi < 4; ++mi)
        a[mi] = *(const half8*)&As[(wm * 64 + mi * 16 + l15) * 64 + ((kb ^ l7) << 3)];
#pragma unroll
      for (int ni = 0; ni < 4; ++ni)
        b[ni] = *(const half8*)&Bs[(wn * 64 + ni * 16 + l15) * 64 + ((kb ^ l7) << 3)];
#pragma unroll
      for (int mi = 0; mi < 4; ++mi)
#pragma unroll
        for (int ni = 0; ni < 4; ++ni)
          acc[mi][ni] = __builtin_amdgcn_mfma_f32_16x16x32_f16(a[mi], b[ni], acc[mi][ni], 0, 0, 0);
    }
  }

#pragma unroll
  for (int mi = 0; mi < 4; ++mi)
#pragma unroll
    for (int ni = 0; ni < 4; ++ni) {
      const size_t col = col0 + wn * 64 + ni * 16 + l15;
      const float bv = bias[col];
#pragma unroll
      for (int ri = 0; ri < 4; ++ri) {
        const size_t row = row0 + wm * 64 + mi * 16 + kq * 4 + ri;
        float v = acc[mi][ni][ri] + bv;
        C[row * N + col] = (h16)fmaxf(v, 0.f);
      }
    }
}

// ---- fused embedding gather + interaction.
// One wave per batch row. T = [x ; emb rows] (27x128 fp16 in LDS, padded to
// 32x136). Gram via 32x32-from-16x16x32 MFMA. Writes z[b] = [x(128) |
// tril(Z)(351) | 0 pad(33)] as fp16 [B,512].
__global__ __launch_bounds__(256) void interact_k(
    const h16* __restrict__ X, const float* __restrict__ emb,
    const int* __restrict__ lSi, h16* __restrict__ z) {
  __shared__ __align__(16) h16 T[4][32][136];
  const int lane = threadIdx.x & 63;
  const int wv = threadIdx.x >> 6;
  const size_t b = (size_t)blockIdx.x * 4 + wv;

  // zero pad rows 27..31 (only cols < 128 are ever read by MFMA)
  for (int i = lane; i < 5 * 128; i += 64)
    T[wv][27 + (i >> 7)][i & 127] = (h16)0.f;

  // row 0 = x; also copy into z[:,0:128]
  {
    half2v v = *(const half2v*)(X + b * 128 + lane * 2);
    *(half2v*)&T[wv][0][lane * 2] = v;
    *(half2v*)(z + b * 512 + lane * 2) = v;
  }
  // rows 1..26 = embedding rows (f32 -> fp16)
  for (int t = 0; t < NTAB; ++t) {
    int idx = lSi[t * NB + (int)b];
    f32x2 v = *(const f32x2*)(emb + ((size_t)t * NR + idx) * 128 + lane * 2);
    half2v h;
    h[0] = (h16)v.x;
    h[1] = (h16)v.y;
    *(half2v*)&T[wv][1 + t][lane * 2] = h;
  }
  // zero z pad cols 479..511
  if (lane < 33) z[b * 512 + 479 + lane] = (h16)0.f;

  __syncthreads();

  f32x4 acc00 = {}, acc10 = {}, acc11 = {};
  const int l15 = lane & 15;
  const int kq = lane >> 4;
#pragma unroll
  for (int kk = 0; kk < 4; ++kk) {
    const int ko = kk * 32 + kq * 8;
    half8 a0 = *(const half8*)&T[wv][l15][ko];
    half8 a1 = *(const half8*)&T[wv][16 + l15][ko];
    acc00 = __builtin_amdgcn_mfma_f32_16x16x32_f16(a0, a0, acc00, 0, 0, 0);
    acc10 = __builtin_amdgcn_mfma_f32_16x16x32_f16(a1, a0, acc10, 0, 0, 0);
    acc11 = __builtin_amdgcn_mfma_f32_16x16x32_f16(a1, a1, acc11, 0, 0, 0);
  }
  // write strictly-lower-triangular entries: p = i*(i-1)/2 + j
  h16* zr = z + b * 512 + 128;
#pragma unroll
  for (int ri = 0; ri < 4; ++ri) {
    int i0 = kq * 4 + ri;       // rows 0..15
    int i1 = 16 + i0;           // rows 16..31
    if (l15 < i0) zr[i0 * (i0 - 1) / 2 + l15] = (h16)acc00[ri];
    if (i1 < 27) {
      zr[i1 * (i1 - 1) / 2 + l15] = (h16)acc10[ri];  // cols 0..15 always < i1
      int j1 = 16 + l15;
      if (j1 < i1) zr[i1 * (i1 - 1) / 2 + j1] = (h16)acc11[ri];
    }
  }
}

// ---- final layer: out[b] = sigmoid(U3[b,:256] . tw4 + tb4), f32 out
__global__ __launch_bounds__(256) void top4_k(
    const h16* __restrict__ U, const float* __restrict__ w,
    const float* __restrict__ bias, float* __restrict__ out) {
  int r = blockIdx.x * 256 + threadIdx.x;
  const h16* ur = U + (size_t)r * 256;
  float acc = 0.f;
#pragma unroll
  for (int k0 = 0; k0 < 256; k0 += 8) {
    half8 v = *(const half8*)&ur[k0];
#pragma unroll
    for (int j = 0; j < 8; ++j) acc += (float)v[j] * w[k0 + j];
  }
  acc += bias[0];
  out[r] = 1.f / (1.f + expf(-acc));
}

extern "C" void kernel_launch(void* const* d_in, const int* in_sizes, int n_in,
                              void* d_out, int out_size, void* d_ws, size_t ws_size,
                              hipStream_t stream) {
  const float* dense_x = (const float*)d_in[0];
  const int* lSi = (const int*)d_in[2];
  const float* emb = (const float*)d_in[3];
  const float* bw0 = (const float*)d_in[4];
  const float* bb0 = (const float*)d_in[5];
  const float* bw1 = (const float*)d_in[6];
  const float* bb1 = (const float*)d_in[7];
  const float* bw2 = (const float*)d_in[8];
  const float* bb2 = (const float*)d_in[9];
  const float* tw0 = (const float*)d_in[10];
  const float* tb0 = (const float*)d_in[11];
  const float* tw1 = (const float*)d_in[12];
  const float* tb1 = (const float*)d_in[13];
  const float* tw2 = (const float*)d_in[14];
  const float* tb2 = (const float*)d_in[15];
  const float* tw3 = (const float*)d_in[16];
  const float* tb3 = (const float*)d_in[17];
  const float* tw4 = (const float*)d_in[18];
  const float* tb4 = (const float*)d_in[19];
  float* out = (float*)d_out;

  char* ws = (char*)d_ws;
  const size_t MB = (size_t)1 << 20;
  // live ranges allow this aliasing (sequential stream order):
  h16* Y0 = (h16*)(ws + 0 * MB);    // [B,512]   16MB   (dead after L1)
  h16* Y1 = (h16*)(ws + 16 * MB);   // [B,256]    8MB   (dead after L2)
  h16* Xc = (h16*)(ws + 24 * MB);   // [B,128]    4MB   (dead after interact)
  h16* Zz = (h16*)(ws + 32 * MB);   // [B,512]   16MB   (dead after T0)
  h16* U0 = (h16*)(ws + 48 * MB);   // [B,1024]  32MB   (dead after T1)
  h16* U1 = (h16*)(ws + 0 * MB);    // [B,1024]  32MB   reuses Y0/Y1/Xc
  h16* U2 = (h16*)(ws + 32 * MB);   // [B,512]   16MB   reuses Zz
  h16* U3 = (h16*)(ws + 48 * MB);   // [B,256]    8MB   reuses U0
  h16* w1p = (h16*)(ws + 80 * MB);  // fp16 weights, ~4.8MB total
  h16* w2p = w1p + 256 * 512;
  h16* t0p = w2p + 128 * 256;
  h16* t1p = t0p + 1024 * 512;
  h16* t2p = t1p + 1024 * 1024;
  h16* t3p = t2p + 512 * 1024;
  (void)in_sizes; (void)n_in; (void)out_size; (void)ws_size;

  // weight conversions (fp16, K padded where needed)
  cvt_k<<<(256 * 512 + 255) / 256, 256, 0, stream>>>(bw1, w1p, 256, 512, 512);
  cvt_k<<<(128 * 256 + 255) / 256, 256, 0, stream>>>(bw2, w2p, 128, 256, 256);
  cvt_k<<<(1024 * 512 + 255) / 256, 256, 0, stream>>>(tw0, t0p, 1024, 479, 512);
  cvt_k<<<(1024 * 1024 + 255) / 256, 256, 0, stream>>>(tw1, t1p, 1024, 1024, 1024);
  cvt_k<<<(512 * 1024 + 255) / 256, 256, 0, stream>>>(tw2, t2p, 512, 1024, 1024);
  cvt_k<<<(256 * 512 + 255) / 256, 256, 0, stream>>>(tw3, t3p, 256, 512, 512);

  bot0_k<<<NB * 512 / 256, 256, 0, stream>>>(dense_x, bw0, bb0, Y0);
  gemm_h<<<dim3(NB / 128, 2), 256, 0, stream>>>(Y0, w1p, bb1, Y1, 256, 512);
  gemm_h<<<dim3(NB / 128, 1), 256, 0, stream>>>(Y1, w2p, bb2, Xc, 128, 256);
  interact_k<<<NB / 4, 256, 0, stream>>>(Xc, emb, lSi, Zz);
  gemm_h<<<dim3(NB / 128, 8), 256, 0, stream>>>(Zz, t0p, tb0, U0, 1024, 512);
  gemm_h<<<dim3(NB / 128, 8), 256, 0, stream>>>(U0, t1p, tb1, U1, 1024, 1024);
  gemm_h<<<dim3(NB / 128, 4), 256, 0, stream>>>(U1, t2p, tb2, U2, 512, 1024);
  gemm_h<<<dim3(NB / 128, 2), 256, 0, stream>>>(U2, t3p, tb3, U3, 256, 512);
  top4_k<<<NB / 256, 256, 0, stream>>>(U3, tw4, tb4, out);
}

// Round 2
// 216.893 us; speedup vs baseline: 1.0501x; 1.0501x over previous
//
#include <hip/hip_runtime.h>
#include <cstdint>
#include <cstddef>

typedef _Float16 h16;
typedef __attribute__((ext_vector_type(8))) _Float16 half8;
typedef __attribute__((ext_vector_type(2))) _Float16 half2v;
typedef __attribute__((ext_vector_type(4))) float f32x4;
typedef __attribute__((ext_vector_type(2))) float f32x2;

#define NB 16384
#define NTAB 26
#define NR 100000

__device__ __forceinline__ void gload16(const void* g, void* l) {
  __builtin_amdgcn_global_load_lds(
      (const __attribute__((address_space(1))) unsigned int*)g,
      (__attribute__((address_space(3))) unsigned int*)l, 16, 0, 0);
}

// ---- bottom layer 0: Y[B,512] = relu(x[B,13] @ W0[512,13]^T + b0), fp16 out
__global__ __launch_bounds__(256) void bot0_k(
    const float* __restrict__ x, const float* __restrict__ W,
    const float* __restrict__ bias, h16* __restrict__ Y) {
  int gid = blockIdx.x * 256 + threadIdx.x;
  int row = gid >> 9;
  int n = gid & 511;
  const float* xr = x + row * 13;
  const float* wr = W + n * 13;
  float acc = bias[n];
#pragma unroll
  for (int k = 0; k < 13; ++k) acc += xr[k] * wr[k];
  Y[gid] = (h16)fmaxf(acc, 0.f);
}

// ---- fused f32 -> fp16 weight conversion (all 6 weights, one launch)
// dst segments are contiguous in ws starting at w1p.
__global__ __launch_bounds__(256) void cvt_all_k(
    const float* __restrict__ s0, const float* __restrict__ s1,
    const float* __restrict__ s2, const float* __restrict__ s3,
    const float* __restrict__ s4, const float* __restrict__ s5,
    h16* __restrict__ dst) {
  int b = blockIdx.x;
  const float* src; int K, Kp, i0; size_t doff;
  if (b < 512)       { src=s0; K=512;  Kp=512;  i0=(b-0)*256;    doff=0; }
  else if (b < 640)  { src=s1; K=256;  Kp=256;  i0=(b-512)*256;  doff=131072; }
  else if (b < 2688) { src=s2; K=479;  Kp=512;  i0=(b-640)*256;  doff=163840; }
  else if (b < 6784) { src=s3; K=1024; Kp=1024; i0=(b-2688)*256; doff=688128; }
  else if (b < 8832) { src=s4; K=1024; Kp=1024; i0=(b-6784)*256; doff=1736704; }
  else               { src=s5; K=512;  Kp=512;  i0=(b-8832)*256; doff=2260992; }
  int i = i0 + threadIdx.x;
  int n = i / Kp, k = i - n * Kp;
  dst[doff + i] = (k < K) ? (h16)src[(size_t)n * K + k] : (h16)0.f;
}

// ---- 128x128-tile fp16 MFMA GEMM (kept for small-N layers):
// C[M,N] = relu(A[M,K] @ W[N,K]^T + bias)
__global__ __launch_bounds__(256, 2) void gemm_h(
    const h16* __restrict__ A, const h16* __restrict__ W,
    const float* __restrict__ bias, h16* __restrict__ C, int N, int K) {
  __shared__ __align__(16) h16 As[128 * 64];
  __shared__ __align__(16) h16 Bs[128 * 64];
  const int tid = threadIdx.x;
  const int lane = tid & 63;
  const int wave = tid >> 6;
  const int wm = wave >> 1, wn = wave & 1;
  const size_t row0 = (size_t)blockIdx.x * 128;
  const size_t col0 = (size_t)blockIdx.y * 128;
  const int lr = lane >> 3;
  const int swzc = (((lane & 7) ^ lr) << 3);
  const int l15 = lane & 15;
  const int kq = lane >> 4;
  const int l7 = lane & 7;

  f32x4 acc[4][4] = {};

  for (int k0 = 0; k0 < K; k0 += 64) {
    __syncthreads();
    const h16* ga = A + (row0 + wave * 32 + lr) * (size_t)K + k0 + swzc;
    const h16* gb = W + (col0 + wave * 32 + lr) * (size_t)K + k0 + swzc;
    h16* la = As + wave * 32 * 64;
    h16* lb = Bs + wave * 32 * 64;
#pragma unroll
    for (int i = 0; i < 4; ++i) {
      gload16(ga + (size_t)i * 8 * K, la + i * 8 * 64);
      gload16(gb + (size_t)i * 8 * K, lb + i * 8 * 64);
    }
    asm volatile("s_waitcnt vmcnt(0)" ::: "memory");
    __syncthreads();
#pragma unroll
    for (int kk = 0; kk < 2; ++kk) {
      half8 a[4], b[4];
      const int kb = kk * 4 + kq;
#pragma unroll
      for (int mi = 0; mi < 4; ++mi)
        a[mi] = *(const half8*)&As[(wm * 64 + mi * 16 + l15) * 64 + ((kb ^ l7) << 3)];
#pragma unroll
      for (int ni = 0; ni < 4; ++ni)
        b[ni] = *(const half8*)&Bs[(wn * 64 + ni * 16 + l15) * 64 + ((kb ^ l7) << 3)];
#pragma unroll
      for (int mi = 0; mi < 4; ++mi)
#pragma unroll
        for (int ni = 0; ni < 4; ++ni)
          acc[mi][ni] = __builtin_amdgcn_mfma_f32_16x16x32_f16(a[mi], b[ni], acc[mi][ni], 0, 0, 0);
    }
  }

#pragma unroll
  for (int mi = 0; mi < 4; ++mi)
#pragma unroll
    for (int ni = 0; ni < 4; ++ni) {
      const size_t col = col0 + wn * 64 + ni * 16 + l15;
      const float bv = bias[col];
#pragma unroll
      for (int ri = 0; ri < 4; ++ri) {
        const size_t row = row0 + wm * 64 + mi * 16 + kq * 4 + ri;
        float v = acc[mi][ni][ri] + bv;
        C[row * N + col] = (h16)fmaxf(v, 0.f);
      }
    }
}

// ---- 256-row-tile pipelined fp16 MFMA GEMM for the big top-MLP layers.
// BM=256, BK=64, 8 waves. BN=256: wave grid 2x4 (per-wave 128x64, acc[8][4]);
// BN=128: wave grid 4x2 (per-wave 64x64, acc[4][4]).
// Double-buffered LDS (128KB / 96KB), XOR chunk swizzle, global_load_lds w16.
// Race-free pipeline: stage tile t+1 into buf p^1 during compute of buf p;
// one vmcnt(0)+barrier per K-tile.
template <int BN>
__global__ __launch_bounds__(512, 2) void gemm256(
    const h16* __restrict__ A, const h16* __restrict__ W,
    const float* __restrict__ bias, h16* __restrict__ C, int N, int K) {
  constexpr int WN = (BN == 256) ? 4 : 2;
  constexpr int MR = (BN == 256) ? 8 : 4;  // m-frags per wave
  __shared__ __align__(16) h16 As[2][256 * 64];
  __shared__ __align__(16) h16 Bs[2][BN * 64];
  const int tid = threadIdx.x;
  const int lane = tid & 63;
  const int wave = tid >> 6;
  const int wm = wave / WN, wn = wave % WN;
  const size_t row0 = (size_t)blockIdx.x * 256;
  const size_t col0 = (size_t)blockIdx.y * BN;
  const int l15 = lane & 15;
  const int kq = lane >> 4;
  // staging: thread t covers row (i*64 + t>>3), chunk (t&7) of the 64-elem k
  const int srow = tid >> 3;
  const int sschunk = (tid & 7) ^ (srow & 7);  // swizzled global k-chunk

  f32x4 acc[MR][4] = {};

  const h16* gA = A + (row0 + srow) * (size_t)K + sschunk * 8;
  const h16* gB = W + (col0 + srow) * (size_t)K + sschunk * 8;

  auto stage = [&](int buf, int k0) {
#pragma unroll
    for (int i = 0; i < 4; ++i)
      gload16(gA + (size_t)(i * 64) * K + k0, &As[buf][i * 4096 + tid * 8]);
#pragma unroll
    for (int i = 0; i < BN / 64; ++i)
      gload16(gB + (size_t)(i * 64) * K + k0, &Bs[buf][i * 4096 + tid * 8]);
  };

  stage(0, 0);
  asm volatile("s_waitcnt vmcnt(0)" ::: "memory");
  __syncthreads();

  const int nt = K / 64;
  for (int t = 0; t < nt; ++t) {
    const int p = t & 1;
    if (t + 1 < nt) stage(p ^ 1, (t + 1) * 64);
    // B fragments for both k-steps, all 4 n-frags (held in regs for the tile)
    half8 breg[2][4];
#pragma unroll
    for (int ks = 0; ks < 2; ++ks)
#pragma unroll
      for (int ni = 0; ni < 4; ++ni) {
        const int r = wn * 64 + ni * 16 + l15;
        const int ch = (ks * 4 + kq) ^ (l15 & 7);
        breg[ks][ni] = *(const half8*)&Bs[p][r * 64 + ch * 8];
      }
#pragma unroll
    for (int mi = 0; mi < MR; ++mi) {
      const int r = wm * (MR * 16) + mi * 16 + l15;
      const int ch0 = kq ^ (l15 & 7);
      const int ch1 = (4 + kq) ^ (l15 & 7);
      half8 a0 = *(const half8*)&As[p][r * 64 + ch0 * 8];
      half8 a1 = *(const half8*)&As[p][r * 64 + ch1 * 8];
#pragma unroll
      for (int ni = 0; ni < 4; ++ni)
        acc[mi][ni] = __builtin_amdgcn_mfma_f32_16x16x32_f16(a0, breg[0][ni], acc[mi][ni], 0, 0, 0);
#pragma unroll
      for (int ni = 0; ni < 4; ++ni)
        acc[mi][ni] = __builtin_amdgcn_mfma_f32_16x16x32_f16(a1, breg[1][ni], acc[mi][ni], 0, 0, 0);
    }
    asm volatile("s_waitcnt vmcnt(0)" ::: "memory");
    __syncthreads();
  }

#pragma unroll
  for (int mi = 0; mi < MR; ++mi)
#pragma unroll
    for (int ni = 0; ni < 4; ++ni) {
      const size_t col = col0 + wn * 64 + ni * 16 + l15;
      const float bv = bias[col];
#pragma unroll
      for (int ri = 0; ri < 4; ++ri) {
        const size_t row = row0 + wm * (MR * 16) + mi * 16 + kq * 4 + ri;
        float v = acc[mi][ni][ri] + bv;
        C[row * N + col] = (h16)fmaxf(v, 0.f);
      }
    }
}

// ---- fused embedding gather + interaction.
// One wave per batch row. T = [x ; emb rows] (27x128 fp16 in LDS, padded to
// 32x136). Gram via 16x16x32 MFMA. Writes z[b] = [x(128) | tril(Z)(351)]
// into fp16 [B,512] (cols 479..511 left as-is: t0p weight pad is zero).
__global__ __launch_bounds__(256) void interact_k(
    const h16* __restrict__ X, const float* __restrict__ emb,
    const int* __restrict__ lSi, h16* __restrict__ z) {
  __shared__ __align__(16) h16 T[4][32][136];
  const int lane = threadIdx.x & 63;
  const int wv = threadIdx.x >> 6;
  const size_t b = (size_t)blockIdx.x * 4 + wv;

  for (int i = lane; i < 5 * 128; i += 64)
    T[wv][27 + (i >> 7)][i & 127] = (h16)0.f;

  {
    half2v v = *(const half2v*)(X + b * 128 + lane * 2);
    *(half2v*)&T[wv][0][lane * 2] = v;
    *(half2v*)(z + b * 512 + lane * 2) = v;
  }
  for (int t = 0; t < NTAB; ++t) {
    int idx = lSi[t * NB + (int)b];
    f32x2 v = *(const f32x2*)(emb + ((size_t)t * NR + idx) * 128 + lane * 2);
    half2v h;
    h[0] = (h16)v.x;
    h[1] = (h16)v.y;
    *(half2v*)&T[wv][1 + t][lane * 2] = h;
  }

  __syncthreads();

  f32x4 acc00 = {}, acc10 = {}, acc11 = {};
  const int l15 = lane & 15;
  const int kq = lane >> 4;
#pragma unroll
  for (int kk = 0; kk < 4; ++kk) {
    const int ko = kk * 32 + kq * 8;
    half8 a0 = *(const half8*)&T[wv][l15][ko];
    half8 a1 = *(const half8*)&T[wv][16 + l15][ko];
    acc00 = __builtin_amdgcn_mfma_f32_16x16x32_f16(a0, a0, acc00, 0, 0, 0);
    acc10 = __builtin_amdgcn_mfma_f32_16x16x32_f16(a1, a0, acc10, 0, 0, 0);
    acc11 = __builtin_amdgcn_mfma_f32_16x16x32_f16(a1, a1, acc11, 0, 0, 0);
  }
  h16* zr = z + b * 512 + 128;
#pragma unroll
  for (int ri = 0; ri < 4; ++ri) {
    int i0 = kq * 4 + ri;
    int i1 = 16 + i0;
    if (l15 < i0) zr[i0 * (i0 - 1) / 2 + l15] = (h16)acc00[ri];
    if (i1 < 27) {
      zr[i1 * (i1 - 1) / 2 + l15] = (h16)acc10[ri];
      int j1 = 16 + l15;
      if (j1 < i1) zr[i1 * (i1 - 1) / 2 + j1] = (h16)acc11[ri];
    }
  }
}

// ---- final layer: out[b] = sigmoid(U3[b,:256] . tw4 + tb4), f32 out
__global__ __launch_bounds__(256) void top4_k(
    const h16* __restrict__ U, const float* __restrict__ w,
    const float* __restrict__ bias, float* __restrict__ out) {
  int r = blockIdx.x * 256 + threadIdx.x;
  const h16* ur = U + (size_t)r * 256;
  float acc = 0.f;
#pragma unroll
  for (int k0 = 0; k0 < 256; k0 += 8) {
    half8 v = *(const half8*)&ur[k0];
#pragma unroll
    for (int j = 0; j < 8; ++j) acc += (float)v[j] * w[k0 + j];
  }
  acc += bias[0];
  out[r] = 1.f / (1.f + expf(-acc));
}

extern "C" void kernel_launch(void* const* d_in, const int* in_sizes, int n_in,
                              void* d_out, int out_size, void* d_ws, size_t ws_size,
                              hipStream_t stream) {
  const float* dense_x = (const float*)d_in[0];
  const int* lSi = (const int*)d_in[2];
  const float* emb = (const float*)d_in[3];
  const float* bw0 = (const float*)d_in[4];
  const float* bb0 = (const float*)d_in[5];
  const float* bw1 = (const float*)d_in[6];
  const float* bb1 = (const float*)d_in[7];
  const float* bw2 = (const float*)d_in[8];
  const float* bb2 = (const float*)d_in[9];
  const float* tw0 = (const float*)d_in[10];
  const float* tb0 = (const float*)d_in[11];
  const float* tw1 = (const float*)d_in[12];
  const float* tb1 = (const float*)d_in[13];
  const float* tw2 = (const float*)d_in[14];
  const float* tb2 = (const float*)d_in[15];
  const float* tw3 = (const float*)d_in[16];
  const float* tb3 = (const float*)d_in[17];
  const float* tw4 = (const float*)d_in[18];
  const float* tb4 = (const float*)d_in[19];
  float* out = (float*)d_out;

  char* ws = (char*)d_ws;
  const size_t MB = (size_t)1 << 20;
  // live ranges allow this aliasing (sequential stream order):
  h16* Y0 = (h16*)(ws + 0 * MB);    // [B,512]   16MB   (dead after L1)
  h16* Y1 = (h16*)(ws + 16 * MB);   // [B,256]    8MB   (dead after L2)
  h16* Xc = (h16*)(ws + 24 * MB);   // [B,128]    4MB   (dead after interact)
  h16* Zz = (h16*)(ws + 32 * MB);   // [B,512]   16MB   (dead after T0)
  h16* U0 = (h16*)(ws + 48 * MB);   // [B,1024]  32MB   (dead after T1)
  h16* U1 = (h16*)(ws + 0 * MB);    // [B,1024]  32MB   reuses Y0/Y1/Xc
  h16* U2 = (h16*)(ws + 32 * MB);   // [B,512]   16MB   reuses Zz
  h16* U3 = (h16*)(ws + 48 * MB);   // [B,256]    8MB   reuses U0
  h16* w1p = (h16*)(ws + 80 * MB);  // fp16 weights, contiguous segments
  h16* w2p = w1p + 256 * 512;
  h16* t0p = w2p + 128 * 256;
  h16* t1p = t0p + 1024 * 512;
  h16* t2p = t1p + 1024 * 1024;
  h16* t3p = t2p + 512 * 1024;
  (void)in_sizes; (void)n_in; (void)out_size; (void)ws_size;

  cvt_all_k<<<9344, 256, 0, stream>>>(bw1, bw2, tw0, tw1, tw2, tw3, w1p);

  bot0_k<<<NB * 512 / 256, 256, 0, stream>>>(dense_x, bw0, bb0, Y0);
  gemm_h<<<dim3(NB / 128, 2), 256, 0, stream>>>(Y0, w1p, bb1, Y1, 256, 512);
  gemm_h<<<dim3(NB / 128, 1), 256, 0, stream>>>(Y1, w2p, bb2, Xc, 128, 256);
  interact_k<<<NB / 4, 256, 0, stream>>>(Xc, emb, lSi, Zz);
  gemm256<256><<<dim3(NB / 256, 4), 512, 0, stream>>>(Zz, t0p, tb0, U0, 1024, 512);
  gemm256<256><<<dim3(NB / 256, 4), 512, 0, stream>>>(U0, t1p, tb1, U1, 1024, 1024);
  gemm256<128><<<dim3(NB / 256, 4), 512, 0, stream>>>(U1, t2p, tb2, U2, 512, 1024);
  gemm_h<<<dim3(NB / 128, 2), 256, 0, stream>>>(U2, t3p, tb3, U3, 256, 512);
  top4_k<<<NB / 256, 256, 0, stream>>>(U3, tw4, tb4, out);
}